// Round 4
// baseline (457.272 us; speedup 1.0000x reference)
//
#include <hip/hip_runtime.h>
#include <math.h>

constexpr int B_ = 2, S_ = 1024, DM_ = 1024, NH_ = 16, HD_ = 64;
constexpr long SD = (long)S_ * DM_;   // per-batch hidden stride (1M)
constexpr long SS = (long)S_ * S_;    // per-head attn stride (1M)

typedef _Float16 half8 __attribute__((ext_vector_type(8)));
typedef _Float16 half4 __attribute__((ext_vector_type(4)));
typedef float floatx4 __attribute__((ext_vector_type(4)));

// async global->LDS, 16 B per lane; LDS dst is wave-uniform base + lane*16
__device__ __forceinline__ void gl_lds16(const void* g, void* l) {
    __builtin_amdgcn_global_load_lds(
        (const __attribute__((address_space(1))) void*)g,
        (__attribute__((address_space(3))) void*)l, 16, 0, 0);
}

// ---------------------------------------------------------------------------
// Segmented fp32 -> fp16 convert for ALL inputs in one launch.
// Segments (float4 units): hs 524288 | Wq/Wk/Wv/Wo 262144 each | Wfq/Wfk 1024.
// Total 1,574,912 float4 -> grid 6152 x 256.
// ---------------------------------------------------------------------------
__global__ __launch_bounds__(256) void cvt_all(
    const float* __restrict__ hs,  const float* __restrict__ Wq,
    const float* __restrict__ Wk,  const float* __restrict__ Wv,
    const float* __restrict__ Wo,  const float* __restrict__ Wfq,
    const float* __restrict__ Wfk,
    _Float16* __restrict__ hsH, _Float16* __restrict__ WqH,
    _Float16* __restrict__ WkH, _Float16* __restrict__ WvH,
    _Float16* __restrict__ WoH, _Float16* __restrict__ WfqH,
    _Float16* __restrict__ WfkH)
{
    long i = (long)blockIdx.x * 256 + threadIdx.x;
    const float* src; _Float16* dst; long off;
    if (i < 524288)       { src = hs;  dst = hsH;  off = i; }
    else if (i < 786432)  { src = Wq;  dst = WqH;  off = i - 524288; }
    else if (i < 1048576) { src = Wk;  dst = WkH;  off = i - 786432; }
    else if (i < 1310720) { src = Wv;  dst = WvH;  off = i - 1048576; }
    else if (i < 1572864) { src = Wo;  dst = WoH;  off = i - 1310720; }
    else if (i < 1573888) { src = Wfq; dst = WfqH; off = i - 1572864; }
    else                  { src = Wfk; dst = WfkH; off = i - 1573888; }
    float4 v = ((const float4*)src)[off];
    half4 h = { (_Float16)v.x, (_Float16)v.y, (_Float16)v.z, (_Float16)v.w };
    ((half4*)dst)[off] = h;
}

// ---------------------------------------------------------------------------
// Unified NT MFMA GEMM: C = scale*(A @ W^T) [+bias] [*rsinv fused via skp].
// A: (M x K) k-contiguous fp16. W: (N x K) k-contiguous fp16.
// Batched over z=(b*NH+h) via element strides.
// mode 0: fp32 out (Cf, nontemporal).  mode 1: fp16 out (Ch).
// skp != null: per-row 1/(A[row,:].skz) normalization computed in-kernel
// (skz = sum of 16 column partials), fused into the epilogue — replaces the
// separate rowsum_inv kernel with identical summation order.
// Block 256 = 4 waves in 2x2; wave computes WM x WN via 16x16x32 f16 MFMA.
// BK = 64 staged as two 32-halves.
// ---------------------------------------------------------------------------
template <int BM, int BN, int WM, int WN>
__global__ __launch_bounds__(256) void mm_nt(
    const _Float16* __restrict__ Ap, const _Float16* __restrict__ Wp,
    const float* __restrict__ bias, const float* __restrict__ skp,
    float* __restrict__ Cf,
    _Float16* __restrict__ Ch, int K, int lda, int ldw, int ldc,
    long sAb, long sAh, long sWb, long sWh, long sCb, long sCh,
    float scale, int mode)
{
    constexpr int MI = WM / 16, NI = WN / 16;
    const int z = blockIdx.z, b = z / NH_, h = z % NH_;
    const int wave = threadIdx.x >> 6, lane = threadIdx.x & 63;
    const int m0 = blockIdx.y * BM, n0 = blockIdx.x * BN;
    const int wm = (wave >> 1) * WM, wn = (wave & 1) * WN;
    const int r16 = lane & 15, quad = lane >> 4;

    const _Float16* Az = Ap + (long)b * sAb + (long)h * sAh;
    const _Float16* Wz = Wp + (long)b * sWb + (long)h * sWh;

    __shared__ __align__(16) _Float16 As[2 * BM * 32];
    __shared__ __align__(16) _Float16 Bs[2 * BN * 32];
    __shared__ float skz[128];
    __shared__ float rsinvs[BM];

    // fused pred-normalization prologue (also warms L2 for A staging)
    if (skp) {
        if (threadIdx.x < 128) {
            float s = 0.f;
#pragma unroll
            for (int m = 0; m < 16; ++m)
                s += skp[((long)z * 16 + m) * 128 + threadIdx.x];
            skz[threadIdx.x] = s;
        }
        __syncthreads();
        if (threadIdx.x < BM) {
            const _Float16* p = Az + (long)(m0 + threadIdx.x) * lda;
            float acc = 0.f;
#pragma unroll
            for (int d0 = 0; d0 < 128; d0 += 8) {
                half8 v = *(const half8*)(p + d0);
#pragma unroll
                for (int j = 0; j < 8; ++j)
                    acc = fmaf((float)v[j], skz[d0 + j], acc);
            }
            rsinvs[threadIdx.x] = 1.f / acc;
        }
    }

    floatx4 acc[MI][NI];
#pragma unroll
    for (int i = 0; i < MI; ++i)
#pragma unroll
        for (int j = 0; j < NI; ++j)
#pragma unroll
            for (int r = 0; r < 4; ++r) acc[i][j][r] = 0.f;

    for (int k0 = 0; k0 < K; k0 += 64) {
#pragma unroll
        for (int hf = 0; hf < 2; ++hf) {
#pragma unroll
            for (int c = wave * (BM / 64); c < (wave + 1) * (BM / 64); ++c) {
                const _Float16* g = Az + (long)(m0 + c * 16 + (lane >> 2)) * lda
                                    + k0 + hf * 32 + (lane & 3) * 8;
                gl_lds16(g, &As[hf * BM * 32 + c * 512]);
            }
#pragma unroll
            for (int c = wave * (BN / 64); c < (wave + 1) * (BN / 64); ++c) {
                const _Float16* g = Wz + (long)(n0 + c * 16 + (lane >> 2)) * ldw
                                    + k0 + hf * 32 + (lane & 3) * 8;
                gl_lds16(g, &Bs[hf * BN * 32 + c * 512]);
            }
        }
        __syncthreads();

#pragma unroll
        for (int hf = 0; hf < 2; ++hf) {
            half8 af[MI], bf8[NI];
#pragma unroll
            for (int i = 0; i < MI; ++i)
                af[i] = *(const half8*)&As[hf * BM * 32
                                           + (wm + i * 16 + r16) * 32 + quad * 8];
#pragma unroll
            for (int j = 0; j < NI; ++j)
                bf8[j] = *(const half8*)&Bs[hf * BN * 32
                                            + (wn + j * 16 + r16) * 32 + quad * 8];
#pragma unroll
            for (int i = 0; i < MI; ++i)
#pragma unroll
                for (int j = 0; j < NI; ++j)
                    acc[i][j] = __builtin_amdgcn_mfma_f32_16x16x32_f16(
                        af[i], bf8[j], acc[i][j], 0, 0, 0);
        }
        __syncthreads();
    }

    const long cb = (long)b * sCb + (long)h * sCh;
#pragma unroll
    for (int i = 0; i < MI; ++i) {
#pragma unroll
        for (int j = 0; j < NI; ++j) {
#pragma unroll
            for (int r = 0; r < 4; ++r) {
                int row = m0 + wm + i * 16 + quad * 4 + r;
                int col = n0 + wn + j * 16 + r16;
                float v = acc[i][j][r] * scale;
                if (bias) v += bias[col];
                if (skp) v *= rsinvs[row - m0];
                if (mode == 0)
                    __builtin_nontemporal_store(v, &Cf[cb + (long)row * ldc + col]);
                else
                    Ch[cb + (long)row * ldc + col] = (_Float16)v;
            }
        }
    }
}

// ---------------------------------------------------------------------------
// Fused QKV projection: z = blockIdx.z selects {Q,K,V}. M=2048, N=1024, K=1024.
// BM=64 x BN=128 -> grid (8,32,3) = 768 blocks (3/CU; old 128x128 was 1.5/CU).
// BK=64 two-half staging. Q,K written fp16 row-major; V written fp16
// TRANSPOSED per head: VtH[((b*16+h)*64+d)*1024 + s].
// ---------------------------------------------------------------------------
__global__ __launch_bounds__(256) void qkv_proj(
    const _Float16* __restrict__ hsH,
    const _Float16* __restrict__ W0, const _Float16* __restrict__ W1,
    const _Float16* __restrict__ W2,
    const float* __restrict__ b0, const float* __restrict__ b1,
    const float* __restrict__ b2,
    _Float16* __restrict__ QH, _Float16* __restrict__ KH,
    _Float16* __restrict__ VtH)
{
    const int z = blockIdx.z;
    const _Float16* W = (z == 0) ? W0 : (z == 1) ? W1 : W2;
    const float* bias = (z == 0) ? b0 : (z == 1) ? b1 : b2;

    const int wave = threadIdx.x >> 6, lane = threadIdx.x & 63;
    const int m0 = blockIdx.y * 64, n0 = blockIdx.x * 128;
    const int wm = (wave >> 1) * 32, wn = (wave & 1) * 64;
    const int r16 = lane & 15, quad = lane >> 4;

    __shared__ __align__(16) _Float16 As[2 * 64 * 32];    // 8 KB
    __shared__ __align__(16) _Float16 Bs[2 * 128 * 32];   // 16 KB

    floatx4 acc[2][4];
#pragma unroll
    for (int i = 0; i < 2; ++i)
#pragma unroll
        for (int j = 0; j < 4; ++j)
#pragma unroll
            for (int r = 0; r < 4; ++r) acc[i][j][r] = 0.f;

    for (int k0 = 0; k0 < 1024; k0 += 64) {
#pragma unroll
        for (int hf = 0; hf < 2; ++hf) {
            const _Float16* ga = hsH + (long)(m0 + wave * 16 + (lane >> 2)) * 1024
                                 + k0 + hf * 32 + (lane & 3) * 8;
            gl_lds16(ga, &As[hf * 2048 + wave * 512]);
#pragma unroll
            for (int c = wave * 2; c < wave * 2 + 2; ++c) {
                const _Float16* gb = W + (long)(n0 + c * 16 + (lane >> 2)) * 1024
                                     + k0 + hf * 32 + (lane & 3) * 8;
                gl_lds16(gb, &Bs[hf * 4096 + c * 512]);
            }
        }
        __syncthreads();

#pragma unroll
        for (int hf = 0; hf < 2; ++hf) {
            half8 af[2], bf8[4];
#pragma unroll
            for (int i = 0; i < 2; ++i)
                af[i] = *(const half8*)&As[hf * 2048
                                           + (wm + i * 16 + r16) * 32 + quad * 8];
#pragma unroll
            for (int j = 0; j < 4; ++j)
                bf8[j] = *(const half8*)&Bs[hf * 4096
                                            + (wn + j * 16 + r16) * 32 + quad * 8];
#pragma unroll
            for (int i = 0; i < 2; ++i)
#pragma unroll
                for (int j = 0; j < 4; ++j)
                    acc[i][j] = __builtin_amdgcn_mfma_f32_16x16x32_f16(
                        af[i], bf8[j], acc[i][j], 0, 0, 0);
        }
        __syncthreads();
    }

    _Float16* dst = (z == 0) ? QH : KH;
#pragma unroll
    for (int i = 0; i < 2; ++i) {
#pragma unroll
        for (int j = 0; j < 4; ++j) {
#pragma unroll
            for (int r = 0; r < 4; ++r) {
                int row = m0 + wm + i * 16 + quad * 4 + r;
                int col = n0 + wn + j * 16 + r16;
                float v = acc[i][j][r] + bias[col];
                if (z < 2) {
                    dst[(long)row * 1024 + col] = (_Float16)v;
                } else {
                    int bb = row >> 10, s = row & 1023;
                    int hh = col >> 6, d = col & 63;
                    VtH[((((long)bb * 16 + hh) * 64 + d) << 10) | s] = (_Float16)v;
                }
            }
        }
    }
}

// ---------------------------------------------------------------------------
// Fused attention block: per (b,h) and 32-row Q block:
//   scores = Q Kh^T (MFMA, fragments straight from global/L2, K=64)
//   softmax in-register (wave shfl_xor + cross-wave LDS reduce)
//   write normalized probs once to trueA (fp32, nontemporal) and keep fp16 P
//   in XOR-swizzled LDS; ctx = P @ V, wave = (mi-half x d-slice), full-K
//   accumulation per wave -> NO cross-wave k-reduce (saves 2 barriers + LDS
//   round trip vs the previous kr-split).
// Block = 512 thr (8 waves). Scores: wave w owns cols w*128..w*128+128.
// ---------------------------------------------------------------------------
__global__ __launch_bounds__(512) void attn_fused(
    const _Float16* __restrict__ Q, const _Float16* __restrict__ K,
    const _Float16* __restrict__ Vt, float* __restrict__ trueA,
    _Float16* __restrict__ ctx)
{
    const int z = blockIdx.y, b = z >> 4, h = z & 15;
    const int m0 = blockIdx.x * 32;
    const int wave = threadIdx.x >> 6, lane = threadIdx.x & 63;
    const int r16 = lane & 15, quad = lane >> 4;
    const int c0 = wave * 128;

    __shared__ __align__(16) _Float16 Ps[32 * 1024];   // 64 KB, phase-aliased
    float* redmx = (float*)Ps;          // [8][32]
    float* redsm = (float*)Ps + 256;    // [8][32]

    const _Float16* Qb = Q + (long)b * SD + h * 64;
    const _Float16* Kb = K + (long)b * SD + h * 64;

    // ---- scores: rows m0..m0+31, cols c0..c0+127, K=64
    half8 af[2][2];
#pragma unroll
    for (int mi = 0; mi < 2; ++mi)
#pragma unroll
        for (int ks = 0; ks < 2; ++ks)
            af[mi][ks] = *(const half8*)&Qb[(long)(m0 + mi * 16 + r16) * DM_
                                            + ks * 32 + quad * 8];

    floatx4 acc[2][8];
#pragma unroll
    for (int mi = 0; mi < 2; ++mi)
#pragma unroll
        for (int nj = 0; nj < 8; ++nj)
#pragma unroll
            for (int r = 0; r < 4; ++r) acc[mi][nj][r] = 0.f;

#pragma unroll
    for (int ks = 0; ks < 2; ++ks) {
#pragma unroll
        for (int nj = 0; nj < 8; ++nj) {
            half8 bf = *(const half8*)&Kb[(long)(c0 + nj * 16 + r16) * DM_
                                          + ks * 32 + quad * 8];
            acc[0][nj] = __builtin_amdgcn_mfma_f32_16x16x32_f16(
                af[0][ks], bf, acc[0][nj], 0, 0, 0);
            acc[1][nj] = __builtin_amdgcn_mfma_f32_16x16x32_f16(
                af[1][ks], bf, acc[1][nj], 0, 0, 0);
        }
    }

    // ---- row max over all 1024 cols
    float rmx[2][4];
#pragma unroll
    for (int mi = 0; mi < 2; ++mi)
#pragma unroll
        for (int r = 0; r < 4; ++r) {
            float m = acc[mi][0][r];
#pragma unroll
            for (int nj = 1; nj < 8; ++nj) m = fmaxf(m, acc[mi][nj][r]);
#pragma unroll
            for (int o = 1; o <= 8; o <<= 1) m = fmaxf(m, __shfl_xor(m, o, 64));
            rmx[mi][r] = m;
        }
    if (r16 == 0) {
#pragma unroll
        for (int mi = 0; mi < 2; ++mi)
#pragma unroll
            for (int r = 0; r < 4; ++r)
                redmx[wave * 32 + mi * 16 + quad * 4 + r] = rmx[mi][r];
    }
    __syncthreads();
    float mx[2][4];
#pragma unroll
    for (int mi = 0; mi < 2; ++mi)
#pragma unroll
        for (int r = 0; r < 4; ++r) {
            float m = redmx[mi * 16 + quad * 4 + r];
#pragma unroll
            for (int w = 1; w < 8; ++w)
                m = fmaxf(m, redmx[w * 32 + mi * 16 + quad * 4 + r]);
            mx[mi][r] = m;
        }

    // ---- p = exp((s - max) * 1/8), row sum
    float rsm[2][4];
#pragma unroll
    for (int mi = 0; mi < 2; ++mi)
#pragma unroll
        for (int r = 0; r < 4; ++r) {
            float s = 0.f;
#pragma unroll
            for (int nj = 0; nj < 8; ++nj) {
                float p = __expf((acc[mi][nj][r] - mx[mi][r]) * 0.125f);
                acc[mi][nj][r] = p;
                s += p;
            }
#pragma unroll
            for (int o = 1; o <= 8; o <<= 1) s += __shfl_xor(s, o, 64);
            rsm[mi][r] = s;
        }
    if (r16 == 0) {
#pragma unroll
        for (int mi = 0; mi < 2; ++mi)
#pragma unroll
            for (int r = 0; r < 4; ++r)
                redsm[wave * 32 + mi * 16 + quad * 4 + r] = rsm[mi][r];
    }
    __syncthreads();
    float inv[2][4];
#pragma unroll
    for (int mi = 0; mi < 2; ++mi)
#pragma unroll
        for (int r = 0; r < 4; ++r) {
            float s = 0.f;
#pragma unroll
            for (int w = 0; w < 8; ++w)
                s += redsm[w * 32 + mi * 16 + quad * 4 + r];
            inv[mi][r] = 1.f / s;
        }
    __syncthreads();   // red reads done; Ps region can be overwritten

    // ---- write normalized probs: trueA (fp32 NT) + Ps (fp16, XOR-swizzled)
    float* Ta = trueA + (long)z * SS + (long)m0 * S_;
#pragma unroll
    for (int mi = 0; mi < 2; ++mi) {
#pragma unroll
        for (int r = 0; r < 4; ++r) {
            const int row = mi * 16 + quad * 4 + r;
            const int sw = (row & 7) << 3;
            const float iv = inv[mi][r];
#pragma unroll
            for (int nj = 0; nj < 8; ++nj) {
                const int col = c0 + nj * 16 + r16;
                const float v = acc[mi][nj][r] * iv;
                __builtin_nontemporal_store(v, &Ta[(long)row * S_ + col]);
                Ps[row * 1024 + (col ^ sw)] = (_Float16)v;
            }
        }
    }
    __syncthreads();   // Ps complete

    // ---- ctx = P @ V: wave = (mi = wave>>2, d-slice = (wave&3)*16), full K
    const int mi = wave >> 2, d0 = (wave & 3) * 16;
    const _Float16* Vb = Vt + ((long)z * 64 + d0 + r16) * (long)S_;
    floatx4 c2;
#pragma unroll
    for (int r = 0; r < 4; ++r) c2[r] = 0.f;

    const int swz = (r16 & 7) << 3;
#pragma unroll 8
    for (int k0 = 0; k0 < 1024; k0 += 32) {
        half8 pa = *(const half8*)&Ps[(mi * 16 + r16) * 1024
                                      + ((k0 + quad * 8) ^ swz)];
        half8 vf = *(const half8*)&Vb[k0 + quad * 8];
        c2 = __builtin_amdgcn_mfma_f32_16x16x32_f16(pa, vf, c2, 0, 0, 0);
    }

    _Float16* Cb = ctx + (long)b * SD + h * 64;
#pragma unroll
    for (int r = 0; r < 4; ++r) {
        const int srow = m0 + mi * 16 + quad * 4 + r;
        Cb[(long)srow * DM_ + d0 + r16] = (_Float16)c2[r];
    }
}

// ---------------------------------------------------------------------------
// Hedgehog feature map, both tensors in one launch (blockIdx.z: 0=fq, 1=fk).
// Per (b,h): Y = Xh @ Wf^T + bf (K=64), out = fp16 [exp(Y)|exp(-Y)] into
// (B,H,S,128). For fk, per-block column partial sums are written to
// skp[(z*16+mb)*128 + c] (deterministic, no atomics) for the analytic pred
// row-sum.
// ---------------------------------------------------------------------------
__global__ __launch_bounds__(256) void feat_map2(
    const _Float16* __restrict__ QH, const _Float16* __restrict__ KH,
    const _Float16* __restrict__ Wfq, const _Float16* __restrict__ Wfk,
    const float* __restrict__ bfq, const float* __restrict__ bfk,
    _Float16* __restrict__ fqH, _Float16* __restrict__ fkH,
    float* __restrict__ skp)
{
    const int which = blockIdx.z;
    const _Float16* Xh = which ? KH : QH;
    const _Float16* Wf = which ? Wfk : Wfq;
    const float* bf    = which ? bfk : bfq;
    _Float16* outH     = which ? fkH : fqH;

    const int z = blockIdx.y, b = z >> 4, h = z & 15;
    const int mb = blockIdx.x, m0 = mb * 64;
    __shared__ float Xs[64][65];
    __shared__ float Ws[64][65];
    __shared__ float red[16][128];
    const _Float16* Xb = Xh + (long)b * SD + h * 64;
    for (int i = threadIdx.x; i < 4096; i += 256) {
        int r = i >> 6, c = i & 63;
        Xs[r][c] = (float)Xb[(long)(m0 + r) * 1024 + c];
        Ws[r][c] = (float)Wf[i];
    }
    __syncthreads();
    const int tmg = threadIdx.x >> 4;
    const int tm = tmg * 4, tn = (threadIdx.x & 15) * 4;
    float acc[4][4] = {{0.f}};
    for (int k = 0; k < 64; ++k) {
        float xv[4], wv[4];
#pragma unroll
        for (int i = 0; i < 4; ++i) xv[i] = Xs[tm + i][k];
#pragma unroll
        for (int j = 0; j < 4; ++j) wv[j] = Ws[tn + j][k];
#pragma unroll
        for (int i = 0; i < 4; ++i)
#pragma unroll
            for (int j = 0; j < 4; ++j) acc[i][j] = fmaf(xv[i], wv[j], acc[i][j]);
    }
    float sp[4] = {0.f, 0.f, 0.f, 0.f}, sn[4] = {0.f, 0.f, 0.f, 0.f};
#pragma unroll
    for (int i = 0; i < 4; ++i) {
        long base = ((long)z * S_ + m0 + tm + i) * 128;
#pragma unroll
        for (int j = 0; j < 4; ++j) {
            float y = acc[i][j] + bf[tn + j];
            float ep = expf(y), en = expf(-y);
            outH[base + tn + j]      = (_Float16)ep;
            outH[base + 64 + tn + j] = (_Float16)en;
            sp[j] += ep; sn[j] += en;
        }
    }
    if (which) {
#pragma unroll
        for (int j = 0; j < 4; ++j) {
            red[tmg][tn + j]      = sp[j];
            red[tmg][64 + tn + j] = sn[j];
        }
        __syncthreads();
        if (threadIdx.x < 128) {
            float s = 0.f;
#pragma unroll
            for (int g = 0; g < 16; ++g) s += red[g][threadIdx.x];
            skp[((long)z * 16 + mb) * 128 + threadIdx.x] = s;
        }
    }
}

// ---------------------------------------------------------------------------
extern "C" void kernel_launch(void* const* d_in, const int* in_sizes, int n_in,
                              void* d_out, int out_size, void* d_ws, size_t ws_size,
                              hipStream_t stream)
{
    (void)in_sizes; (void)n_in; (void)out_size; (void)ws_size;

    const float* hs  = (const float*)d_in[0];
    const float* Wq  = (const float*)d_in[1];
    const float* bq  = (const float*)d_in[2];
    const float* Wk  = (const float*)d_in[3];
    const float* bk  = (const float*)d_in[4];
    const float* Wv  = (const float*)d_in[5];
    const float* bv  = (const float*)d_in[6];
    const float* Wo  = (const float*)d_in[7];
    const float* bo  = (const float*)d_in[8];
    const float* Wfq = (const float*)d_in[9];
    const float* bfq = (const float*)d_in[10];
    const float* Wfk = (const float*)d_in[11];
    const float* bfk = (const float*)d_in[12];

    float* out0  = (float*)d_out;                       // (B,S,DM)
    float* pred  = out0 + (long)B_ * S_ * DM_;          // (B,H,S,S)
    float* trueA = pred + (long)B_ * NH_ * S_ * S_;     // (B,H,S,S)

    // workspace carve (halves), ~45 MB total
    _Float16* hsH  = (_Float16*)d_ws;                   // 2M
    _Float16* WqH  = hsH + 2 * 1024 * 1024;             // 1M each
    _Float16* WkH  = WqH + 1024 * 1024;
    _Float16* WvH  = WkH + 1024 * 1024;
    _Float16* WoH  = WvH + 1024 * 1024;
    _Float16* WfqH = WoH + 1024 * 1024;                 // 4096 each
    _Float16* WfkH = WfqH + 4096;
    _Float16* QH   = WfkH + 4096;                       // 2M each
    _Float16* KH   = QH + 2 * 1024 * 1024;
    _Float16* VtH  = KH + 2 * 1024 * 1024;              // (B,H,D,S)
    _Float16* ctxH = VtH + 2 * 1024 * 1024;             // (B,S,DM)
    _Float16* fqH  = ctxH + 2 * 1024 * 1024;            // (B,H,S,128)
    _Float16* fkH  = fqH + (long)B_ * NH_ * S_ * 128;

    // skp (256 KB) reuses WqH region (dead after qkv_proj, written by
    // feat_map2). Fully overwritten with plain stores before being read.
    float* skp = (float*)WqH;

    const dim3 blk(256);

    // 0) all fp32 -> fp16 input conversions, one launch
    cvt_all<<<6152, blk, 0, stream>>>(
        hs, Wq, Wk, Wv, Wo, Wfq, Wfk,
        hsH, WqH, WkH, WvH, WoH, WfqH, WfkH);

    // 1) fused QKV projection (V transposed per head), 768 blocks
    qkv_proj<<<dim3(8, 32, 3), blk, 0, stream>>>(
        hsH, WqH, WkH, WvH, bq, bk, bv, QH, KH, VtH);

    // 2) fused scores -> softmax -> trueA + ctx
    attn_fused<<<dim3(32, 32), dim3(512), 0, stream>>>(
        QH, KH, VtH, trueA, ctxH);

    // 3) outputs = ctx @ Wo^T + bo (fp32 out); 64x64 tile -> 512 blocks (2/CU)
    mm_nt<64, 64, 32, 32><<<dim3(16, 32, 1), blk, 0, stream>>>(
        ctxH, WoH, bo, nullptr, out0, nullptr, 1024, 1024, 1024, 1024,
        0, 0, 0, 0, 0, 0, 1.f, 0);

    // 4) feature maps -> fqH, fkH + per-block fk column partials (skp)
    feat_map2<<<dim3(16, 32, 2), blk, 0, stream>>>(
        QH, KH, WfqH, WfkH, bfq, bfk, fqH, fkH, skp);

    // 5) pred = (fq @ fk^T) / rowsum, normalization fully fused (skp path)
    mm_nt<128, 128, 64, 64><<<dim3(8, 8, 32), blk, 0, stream>>>(
        fqH, fkH, nullptr, skp, pred, nullptr, 128, 128, 128, 1024,
        (long)16 * S_ * 128, (long)S_ * 128,
        (long)16 * S_ * 128, (long)S_ * 128,
        16 * SS, SS, 1.f, 0);
}

// Round 6
// 448.838 us; speedup vs baseline: 1.0188x; 1.0188x over previous
//
#include <hip/hip_runtime.h>
#include <math.h>

constexpr int B_ = 2, S_ = 1024, DM_ = 1024, NH_ = 16, HD_ = 64;
constexpr long SD = (long)S_ * DM_;   // per-batch hidden stride (1M)
constexpr long SS = (long)S_ * S_;    // per-head attn stride (1M)

typedef _Float16 half8 __attribute__((ext_vector_type(8)));
typedef _Float16 half4 __attribute__((ext_vector_type(4)));
typedef float floatx4 __attribute__((ext_vector_type(4)));

// async global->LDS, 16 B per lane; LDS dst is wave-uniform base + lane*16
__device__ __forceinline__ void gl_lds16(const void* g, void* l) {
    __builtin_amdgcn_global_load_lds(
        (const __attribute__((address_space(1))) void*)g,
        (__attribute__((address_space(3))) void*)l, 16, 0, 0);
}

__device__ __forceinline__ void nt_store4(const floatx4& v, float* p) {
    __builtin_nontemporal_store(v, (floatx4*)p);
}

// ---------------------------------------------------------------------------
// Segmented fp32 -> fp16 convert for ALL inputs in one launch.
// ---------------------------------------------------------------------------
__global__ __launch_bounds__(256) void cvt_all(
    const float* __restrict__ hs,  const float* __restrict__ Wq,
    const float* __restrict__ Wk,  const float* __restrict__ Wv,
    const float* __restrict__ Wo,  const float* __restrict__ Wfq,
    const float* __restrict__ Wfk,
    _Float16* __restrict__ hsH, _Float16* __restrict__ WqH,
    _Float16* __restrict__ WkH, _Float16* __restrict__ WvH,
    _Float16* __restrict__ WoH, _Float16* __restrict__ WfqH,
    _Float16* __restrict__ WfkH)
{
    long i = (long)blockIdx.x * 256 + threadIdx.x;
    const float* src; _Float16* dst; long off;
    if (i < 524288)       { src = hs;  dst = hsH;  off = i; }
    else if (i < 786432)  { src = Wq;  dst = WqH;  off = i - 524288; }
    else if (i < 1048576) { src = Wk;  dst = WkH;  off = i - 786432; }
    else if (i < 1310720) { src = Wv;  dst = WvH;  off = i - 1048576; }
    else if (i < 1572864) { src = Wo;  dst = WoH;  off = i - 1310720; }
    else if (i < 1573888) { src = Wfq; dst = WfqH; off = i - 1572864; }
    else                  { src = Wfk; dst = WfkH; off = i - 1573888; }
    float4 v = ((const float4*)src)[off];
    half4 h = { (_Float16)v.x, (_Float16)v.y, (_Float16)v.z, (_Float16)v.w };
    ((half4*)dst)[off] = h;
}

// ---------------------------------------------------------------------------
// Unified NT MFMA GEMM: C = scale*(A @ W^T) [+bias] [*rsinv fused via skp].
// SWAPPED-OPERAND epilogue: mfma(W-frag, A-frag) puts 4 CONSECUTIVE output
// cols in each thread's regs (col = quad*4+r, row = r16) -> float4/half4
// stores (4x fewer store instructions than the scalar-store layout).
// BK = 64 staged as two 32-halves via global_load_lds.
// ---------------------------------------------------------------------------
template <int BM, int BN, int WM, int WN>
__global__ __launch_bounds__(256) void mm_nt(
    const _Float16* __restrict__ Ap, const _Float16* __restrict__ Wp,
    const float* __restrict__ bias, const float* __restrict__ skp,
    float* __restrict__ Cf,
    _Float16* __restrict__ Ch, int K, int lda, int ldw, int ldc,
    long sAb, long sAh, long sWb, long sWh, long sCb, long sCh,
    float scale, int mode)
{
    constexpr int MI = WM / 16, NI = WN / 16;
    const int z = blockIdx.z, b = z / NH_, h = z % NH_;
    const int wave = threadIdx.x >> 6, lane = threadIdx.x & 63;
    const int m0 = blockIdx.y * BM, n0 = blockIdx.x * BN;
    const int wm = (wave >> 1) * WM, wn = (wave & 1) * WN;
    const int r16 = lane & 15, quad = lane >> 4;

    const _Float16* Az = Ap + (long)b * sAb + (long)h * sAh;
    const _Float16* Wz = Wp + (long)b * sWb + (long)h * sWh;

    __shared__ __align__(16) _Float16 As[2 * BM * 32];
    __shared__ __align__(16) _Float16 Bs[2 * BN * 32];
    __shared__ float skz[128];
    __shared__ float rsinvs[BM];

    // fused pred-normalization prologue (also warms L2 for A staging)
    if (skp) {
        if (threadIdx.x < 128) {
            float s = 0.f;
#pragma unroll
            for (int m = 0; m < 16; ++m)
                s += skp[((long)z * 16 + m) * 128 + threadIdx.x];
            skz[threadIdx.x] = s;
        }
        __syncthreads();
        if (threadIdx.x < BM) {
            const _Float16* p = Az + (long)(m0 + threadIdx.x) * lda;
            float acc = 0.f;
#pragma unroll
            for (int d0 = 0; d0 < 128; d0 += 8) {
                half8 v = *(const half8*)(p + d0);
#pragma unroll
                for (int j = 0; j < 8; ++j)
                    acc = fmaf((float)v[j], skz[d0 + j], acc);
            }
            rsinvs[threadIdx.x] = 1.f / acc;
        }
    }

    floatx4 acc[MI][NI];
#pragma unroll
    for (int i = 0; i < MI; ++i)
#pragma unroll
        for (int j = 0; j < NI; ++j)
#pragma unroll
            for (int r = 0; r < 4; ++r) acc[i][j][r] = 0.f;

    for (int k0 = 0; k0 < K; k0 += 64) {
#pragma unroll
        for (int hf = 0; hf < 2; ++hf) {
#pragma unroll
            for (int c = wave * (BM / 64); c < (wave + 1) * (BM / 64); ++c) {
                const _Float16* g = Az + (long)(m0 + c * 16 + (lane >> 2)) * lda
                                    + k0 + hf * 32 + (lane & 3) * 8;
                gl_lds16(g, &As[hf * BM * 32 + c * 512]);
            }
#pragma unroll
            for (int c = wave * (BN / 64); c < (wave + 1) * (BN / 64); ++c) {
                const _Float16* g = Wz + (long)(n0 + c * 16 + (lane >> 2)) * ldw
                                    + k0 + hf * 32 + (lane & 3) * 8;
                gl_lds16(g, &Bs[hf * BN * 32 + c * 512]);
            }
        }
        __syncthreads();

#pragma unroll
        for (int hf = 0; hf < 2; ++hf) {
            half8 af[MI], bf8[NI];
#pragma unroll
            for (int i = 0; i < MI; ++i)
                af[i] = *(const half8*)&As[hf * BM * 32
                                           + (wm + i * 16 + r16) * 32 + quad * 8];
#pragma unroll
            for (int j = 0; j < NI; ++j)
                bf8[j] = *(const half8*)&Bs[hf * BN * 32
                                            + (wn + j * 16 + r16) * 32 + quad * 8];
#pragma unroll
            for (int i = 0; i < MI; ++i)
#pragma unroll
                for (int j = 0; j < NI; ++j)
                    acc[i][j] = __builtin_amdgcn_mfma_f32_16x16x32_f16(
                        bf8[j], af[i], acc[i][j], 0, 0, 0);   // SWAPPED
        }
        __syncthreads();
    }

    // epilogue: thread holds row = m0+wm+i*16+r16, cols n0+wn+j*16+quad*4+{0..3}
    const long cb = (long)b * sCb + (long)h * sCh;
#pragma unroll
    for (int i = 0; i < MI; ++i) {
        const int row = m0 + wm + i * 16 + r16;
        const float rs = skp ? rsinvs[row - m0] : 1.f;
#pragma unroll
        for (int j = 0; j < NI; ++j) {
            const int col = n0 + wn + j * 16 + quad * 4;
            floatx4 v;
#pragma unroll
            for (int r = 0; r < 4; ++r) v[r] = acc[i][j][r] * scale;
            if (bias) {
                float4 bv = *(const float4*)&bias[col];
                v[0] += bv.x; v[1] += bv.y; v[2] += bv.z; v[3] += bv.w;
            }
            if (skp) {
#pragma unroll
                for (int r = 0; r < 4; ++r) v[r] *= rs;
            }
            if (mode == 0) {
                nt_store4(v, &Cf[cb + (long)row * ldc + col]);
            } else {
                half4 hv = { (_Float16)v[0], (_Float16)v[1],
                             (_Float16)v[2], (_Float16)v[3] };
                *(half4*)&Ch[cb + (long)row * ldc + col] = hv;
            }
        }
    }
}

// ---------------------------------------------------------------------------
// Fused QKV projection: z = blockIdx.z selects {Q,K,V}. M=2048, N=1024, K=1024.
// Swapped-operand epilogue: Q/K stored as half4 (8 stores/thread vs 32).
// V written fp16 TRANSPOSED per head (scalar, stride dictated by layout).
// ---------------------------------------------------------------------------
__global__ __launch_bounds__(256) void qkv_proj(
    const _Float16* __restrict__ hsH,
    const _Float16* __restrict__ W0, const _Float16* __restrict__ W1,
    const _Float16* __restrict__ W2,
    const float* __restrict__ b0, const float* __restrict__ b1,
    const float* __restrict__ b2,
    _Float16* __restrict__ QH, _Float16* __restrict__ KH,
    _Float16* __restrict__ VtH)
{
    const int z = blockIdx.z;
    const _Float16* W = (z == 0) ? W0 : (z == 1) ? W1 : W2;
    const float* bias = (z == 0) ? b0 : (z == 1) ? b1 : b2;

    const int wave = threadIdx.x >> 6, lane = threadIdx.x & 63;
    const int m0 = blockIdx.y * 64, n0 = blockIdx.x * 128;
    const int wm = (wave >> 1) * 32, wn = (wave & 1) * 64;
    const int r16 = lane & 15, quad = lane >> 4;

    __shared__ __align__(16) _Float16 As[2 * 64 * 32];    // 8 KB
    __shared__ __align__(16) _Float16 Bs[2 * 128 * 32];   // 16 KB

    floatx4 acc[2][4];
#pragma unroll
    for (int i = 0; i < 2; ++i)
#pragma unroll
        for (int j = 0; j < 4; ++j)
#pragma unroll
            for (int r = 0; r < 4; ++r) acc[i][j][r] = 0.f;

    for (int k0 = 0; k0 < 1024; k0 += 64) {
#pragma unroll
        for (int hf = 0; hf < 2; ++hf) {
            const _Float16* ga = hsH + (long)(m0 + wave * 16 + (lane >> 2)) * 1024
                                 + k0 + hf * 32 + (lane & 3) * 8;
            gl_lds16(ga, &As[hf * 2048 + wave * 512]);
#pragma unroll
            for (int c = wave * 2; c < wave * 2 + 2; ++c) {
                const _Float16* gb = W + (long)(n0 + c * 16 + (lane >> 2)) * 1024
                                     + k0 + hf * 32 + (lane & 3) * 8;
                gl_lds16(gb, &Bs[hf * 4096 + c * 512]);
            }
        }
        __syncthreads();

#pragma unroll
        for (int hf = 0; hf < 2; ++hf) {
            half8 af[2], bf8[4];
#pragma unroll
            for (int i = 0; i < 2; ++i)
                af[i] = *(const half8*)&As[hf * 2048
                                           + (wm + i * 16 + r16) * 32 + quad * 8];
#pragma unroll
            for (int j = 0; j < 4; ++j)
                bf8[j] = *(const half8*)&Bs[hf * 4096
                                            + (wn + j * 16 + r16) * 32 + quad * 8];
#pragma unroll
            for (int i = 0; i < 2; ++i)
#pragma unroll
                for (int j = 0; j < 4; ++j)
                    acc[i][j] = __builtin_amdgcn_mfma_f32_16x16x32_f16(
                        bf8[j], af[i], acc[i][j], 0, 0, 0);   // SWAPPED
        }
        __syncthreads();
    }

    _Float16* dst = (z == 0) ? QH : KH;
#pragma unroll
    for (int i = 0; i < 2; ++i) {
        const int row = m0 + wm + i * 16 + r16;
#pragma unroll
        for (int j = 0; j < 4; ++j) {
            const int col = n0 + wn + j * 16 + quad * 4;
            float4 bv = *(const float4*)&bias[col];
            float v0 = acc[i][j][0] + bv.x, v1 = acc[i][j][1] + bv.y;
            float v2 = acc[i][j][2] + bv.z, v3 = acc[i][j][3] + bv.w;
            if (z < 2) {
                half4 hv = { (_Float16)v0, (_Float16)v1,
                             (_Float16)v2, (_Float16)v3 };
                *(half4*)&dst[(long)row * 1024 + col] = hv;
            } else {
                const int bb = row >> 10, s = row & 1023;
                const int hh = col >> 6, d0 = col & 63;
                float vv[4] = { v0, v1, v2, v3 };
#pragma unroll
                for (int r = 0; r < 4; ++r)
                    VtH[((((long)bb * 16 + hh) * 64 + d0 + r) << 10) | s] =
                        (_Float16)vv[r];
            }
        }
    }
}

// ---------------------------------------------------------------------------
// Fused attention block with SWAPPED QK^T: acc[mi][nj][r] holds
// scores[m = m0+mi*16+r16][n = c0+nj*16+quad*4+r] -> softmax row becomes
// lane-local over r16 (reduce = 32 local + shfl_xor 16,32), and trueA/Ps/ctx
// writes vectorize (float4 / half4).
// Block = 512 thr (8 waves). Scores: wave w owns cols w*128..w*128+128.
// PV: wave = (mi = wave>>2, d-slice (wave&3)*16), full-K accumulation.
// ---------------------------------------------------------------------------
__global__ __launch_bounds__(512) void attn_fused(
    const _Float16* __restrict__ Q, const _Float16* __restrict__ K,
    const _Float16* __restrict__ Vt, float* __restrict__ trueA,
    _Float16* __restrict__ ctx)
{
    const int z = blockIdx.y, b = z >> 4, h = z & 15;
    const int m0 = blockIdx.x * 32;
    const int wave = threadIdx.x >> 6, lane = threadIdx.x & 63;
    const int r16 = lane & 15, quad = lane >> 4;
    const int c0 = wave * 128;

    __shared__ __align__(16) _Float16 Ps[32 * 1024];   // 64 KB, phase-aliased
    float* redmx = (float*)Ps;          // [8][32]
    float* redsm = (float*)Ps + 256;    // [8][32]

    const _Float16* Qb = Q + (long)b * SD + h * 64;
    const _Float16* Kb = K + (long)b * SD + h * 64;

    // Q fragments (B-operand after swap): rows m0+mi*16+r16
    half8 qf[2][2];
#pragma unroll
    for (int mi = 0; mi < 2; ++mi)
#pragma unroll
        for (int ks = 0; ks < 2; ++ks)
            qf[mi][ks] = *(const half8*)&Qb[(long)(m0 + mi * 16 + r16) * DM_
                                            + ks * 32 + quad * 8];

    floatx4 acc[2][8];
#pragma unroll
    for (int mi = 0; mi < 2; ++mi)
#pragma unroll
        for (int nj = 0; nj < 8; ++nj)
#pragma unroll
            for (int r = 0; r < 4; ++r) acc[mi][nj][r] = 0.f;

#pragma unroll
    for (int ks = 0; ks < 2; ++ks) {
#pragma unroll
        for (int nj = 0; nj < 8; ++nj) {
            half8 kf = *(const half8*)&Kb[(long)(c0 + nj * 16 + r16) * DM_
                                          + ks * 32 + quad * 8];
            acc[0][nj] = __builtin_amdgcn_mfma_f32_16x16x32_f16(
                kf, qf[0][ks], acc[0][nj], 0, 0, 0);   // SWAPPED
            acc[1][nj] = __builtin_amdgcn_mfma_f32_16x16x32_f16(
                kf, qf[1][ks], acc[1][nj], 0, 0, 0);
        }
    }

    // ---- row max: 32 local values + quad reduce (shfl_xor 16,32)
    float mxl[2];
#pragma unroll
    for (int mi = 0; mi < 2; ++mi) {
        float m = acc[mi][0][0];
#pragma unroll
        for (int nj = 0; nj < 8; ++nj)
#pragma unroll
            for (int r = 0; r < 4; ++r) m = fmaxf(m, acc[mi][nj][r]);
        m = fmaxf(m, __shfl_xor(m, 16, 64));
        m = fmaxf(m, __shfl_xor(m, 32, 64));
        mxl[mi] = m;
    }
    if (quad == 0) {
        redmx[wave * 32 + r16]      = mxl[0];
        redmx[wave * 32 + 16 + r16] = mxl[1];
    }
    __syncthreads();
    float mx[2];
#pragma unroll
    for (int mi = 0; mi < 2; ++mi) {
        float m = redmx[mi * 16 + r16];
#pragma unroll
        for (int w = 1; w < 8; ++w)
            m = fmaxf(m, redmx[w * 32 + mi * 16 + r16]);
        mx[mi] = m;
    }

    // ---- p = exp((s - max)/8), row sum
    float sml[2];
#pragma unroll
    for (int mi = 0; mi < 2; ++mi) {
        float s = 0.f;
#pragma unroll
        for (int nj = 0; nj < 8; ++nj)
#pragma unroll
            for (int r = 0; r < 4; ++r) {
                float p = __expf((acc[mi][nj][r] - mx[mi]) * 0.125f);
                acc[mi][nj][r] = p;
                s += p;
            }
        s += __shfl_xor(s, 16, 64);
        s += __shfl_xor(s, 32, 64);
        sml[mi] = s;
    }
    if (quad == 0) {
        redsm[wave * 32 + r16]      = sml[0];
        redsm[wave * 32 + 16 + r16] = sml[1];
    }
    __syncthreads();
    float inv[2];
#pragma unroll
    for (int mi = 0; mi < 2; ++mi) {
        float s = 0.f;
#pragma unroll
        for (int w = 0; w < 8; ++w) s += redsm[w * 32 + mi * 16 + r16];
        inv[mi] = 1.f / s;
    }
    __syncthreads();   // red reads done; Ps region can be overwritten

    // ---- write normalized probs: trueA (float4 NT) + Ps (half4, XOR-swizzled)
    float* Ta = trueA + (long)z * SS + (long)m0 * S_;
    const int sw = (r16 & 7) << 3;
#pragma unroll
    for (int mi = 0; mi < 2; ++mi) {
        const int row = mi * 16 + r16;
        const float iv = inv[mi];
#pragma unroll
        for (int nj = 0; nj < 8; ++nj) {
            const int col = c0 + nj * 16 + quad * 4;
            floatx4 tv; half4 hv;
#pragma unroll
            for (int r = 0; r < 4; ++r) {
                float v = acc[mi][nj][r] * iv;
                tv[r] = v;
                hv[r] = (_Float16)v;
            }
            nt_store4(tv, &Ta[(long)row * S_ + col]);
            *(half4*)&Ps[row * 1024 + (col ^ sw)] = hv;
        }
    }
    __syncthreads();   // Ps complete

    // ---- ctx = P @ V (swapped): D[d = d0+quad*4+r][m = mi*16+r16]
    const int mi = wave >> 2, d0 = (wave & 3) * 16;
    const _Float16* Vb = Vt + ((long)z * 64 + d0 + r16) * (long)S_;
    floatx4 c2;
#pragma unroll
    for (int r = 0; r < 4; ++r) c2[r] = 0.f;

    const int swz = (r16 & 7) << 3;
#pragma unroll 8
    for (int k0 = 0; k0 < 1024; k0 += 32) {
        half8 pa = *(const half8*)&Ps[(mi * 16 + r16) * 1024
                                      + ((k0 + quad * 8) ^ swz)];
        half8 vf = *(const half8*)&Vb[k0 + quad * 8];
        c2 = __builtin_amdgcn_mfma_f32_16x16x32_f16(vf, pa, c2, 0, 0, 0);
    }

    _Float16* Cb = ctx + (long)b * SD + h * 64;
    half4 cv = { (_Float16)c2[0], (_Float16)c2[1],
                 (_Float16)c2[2], (_Float16)c2[3] };
    *(half4*)&Cb[(long)(m0 + mi * 16 + r16) * DM_ + d0 + quad * 4] = cv;
}

// ---------------------------------------------------------------------------
// Hedgehog feature map, both tensors in one launch (blockIdx.z: 0=fq, 1=fk).
// For fk, per-block column partial sums -> skp (deterministic, no atomics).
// ---------------------------------------------------------------------------
__global__ __launch_bounds__(256) void feat_map2(
    const _Float16* __restrict__ QH, const _Float16* __restrict__ KH,
    const _Float16* __restrict__ Wfq, const _Float16* __restrict__ Wfk,
    const float* __restrict__ bfq, const float* __restrict__ bfk,
    _Float16* __restrict__ fqH, _Float16* __restrict__ fkH,
    float* __restrict__ skp)
{
    const int which = blockIdx.z;
    const _Float16* Xh = which ? KH : QH;
    const _Float16* Wf = which ? Wfk : Wfq;
    const float* bf    = which ? bfk : bfq;
    _Float16* outH     = which ? fkH : fqH;

    const int z = blockIdx.y, b = z >> 4, h = z & 15;
    const int mb = blockIdx.x, m0 = mb * 64;
    __shared__ float Xs[64][65];
    __shared__ float Ws[64][65];
    __shared__ float red[16][128];
    const _Float16* Xb = Xh + (long)b * SD + h * 64;
    for (int i = threadIdx.x; i < 4096; i += 256) {
        int r = i >> 6, c = i & 63;
        Xs[r][c] = (float)Xb[(long)(m0 + r) * 1024 + c];
        Ws[r][c] = (float)Wf[i];
    }
    __syncthreads();
    const int tmg = threadIdx.x >> 4;
    const int tm = tmg * 4, tn = (threadIdx.x & 15) * 4;
    float acc[4][4] = {{0.f}};
    for (int k = 0; k < 64; ++k) {
        float xv[4], wv[4];
#pragma unroll
        for (int i = 0; i < 4; ++i) xv[i] = Xs[tm + i][k];
#pragma unroll
        for (int j = 0; j < 4; ++j) wv[j] = Ws[tn + j][k];
#pragma unroll
        for (int i = 0; i < 4; ++i)
#pragma unroll
            for (int j = 0; j < 4; ++j) acc[i][j] = fmaf(xv[i], wv[j], acc[i][j]);
    }
    float sp[4] = {0.f, 0.f, 0.f, 0.f}, sn[4] = {0.f, 0.f, 0.f, 0.f};
#pragma unroll
    for (int i = 0; i < 4; ++i) {
        long base = ((long)z * S_ + m0 + tm + i) * 128;
#pragma unroll
        for (int j = 0; j < 4; ++j) {
            float y = acc[i][j] + bf[tn + j];
            float ep = expf(y), en = expf(-y);
            outH[base + tn + j]      = (_Float16)ep;
            outH[base + 64 + tn + j] = (_Float16)en;
            sp[j] += ep; sn[j] += en;
        }
    }
    if (which) {
#pragma unroll
        for (int j = 0; j < 4; ++j) {
            red[tmg][tn + j]      = sp[j];
            red[tmg][64 + tn + j] = sn[j];
        }
        __syncthreads();
        if (threadIdx.x < 128) {
            float s = 0.f;
#pragma unroll
            for (int g = 0; g < 16; ++g) s += red[g][threadIdx.x];
            skp[((long)z * 16 + mb) * 128 + threadIdx.x] = s;
        }
    }
}

// ---------------------------------------------------------------------------
extern "C" void kernel_launch(void* const* d_in, const int* in_sizes, int n_in,
                              void* d_out, int out_size, void* d_ws, size_t ws_size,
                              hipStream_t stream)
{
    (void)in_sizes; (void)n_in; (void)out_size; (void)ws_size;

    const float* hs  = (const float*)d_in[0];
    const float* Wq  = (const float*)d_in[1];
    const float* bq  = (const float*)d_in[2];
    const float* Wk  = (const float*)d_in[3];
    const float* bk  = (const float*)d_in[4];
    const float* Wv  = (const float*)d_in[5];
    const float* bv  = (const float*)d_in[6];
    const float* Wo  = (const float*)d_in[7];
    const float* bo  = (const float*)d_in[8];
    const float* Wfq = (const float*)d_in[9];
    const float* bfq = (const float*)d_in[10];
    const float* Wfk = (const float*)d_in[11];
    const float* bfk = (const float*)d_in[12];

    float* out0  = (float*)d_out;                       // (B,S,DM)
    float* pred  = out0 + (long)B_ * S_ * DM_;          // (B,H,S,S)
    float* trueA = pred + (long)B_ * NH_ * S_ * S_;     // (B,H,S,S)

    // workspace carve (halves), ~45 MB total
    _Float16* hsH  = (_Float16*)d_ws;                   // 2M
    _Float16* WqH  = hsH + 2 * 1024 * 1024;             // 1M each
    _Float16* WkH  = WqH + 1024 * 1024;
    _Float16* WvH  = WkH + 1024 * 1024;
    _Float16* WoH  = WvH + 1024 * 1024;
    _Float16* WfqH = WoH + 1024 * 1024;                 // 4096 each
    _Float16* WfkH = WfqH + 4096;
    _Float16* QH   = WfkH + 4096;                       // 2M each
    _Float16* KH   = QH + 2 * 1024 * 1024;
    _Float16* VtH  = KH + 2 * 1024 * 1024;              // (B,H,D,S)
    _Float16* ctxH = VtH + 2 * 1024 * 1024;             // (B,S,DM)
    _Float16* fqH  = ctxH + 2 * 1024 * 1024;            // (B,H,S,128)
    _Float16* fkH  = fqH + (long)B_ * NH_ * S_ * 128;

    // skp (256 KB) reuses WqH region (dead after qkv_proj, written by
    // feat_map2). Fully overwritten with plain stores before being read.
    float* skp = (float*)WqH;

    const dim3 blk(256);

    // 0) all fp32 -> fp16 input conversions, one launch
    cvt_all<<<6152, blk, 0, stream>>>(
        hs, Wq, Wk, Wv, Wo, Wfq, Wfk,
        hsH, WqH, WkH, WvH, WoH, WfqH, WfkH);

    // 1) fused QKV projection (V transposed per head)
    qkv_proj<<<dim3(8, 32, 3), blk, 0, stream>>>(
        hsH, WqH, WkH, WvH, bq, bk, bv, QH, KH, VtH);

    // 2) fused scores -> softmax -> trueA + ctx
    attn_fused<<<dim3(32, 32), dim3(512), 0, stream>>>(
        QH, KH, VtH, trueA, ctxH);

    // 3) outputs = ctx @ Wo^T + bo (fp32 out)
    mm_nt<64, 64, 32, 32><<<dim3(16, 32, 1), blk, 0, stream>>>(
        ctxH, WoH, bo, nullptr, out0, nullptr, 1024, 1024, 1024, 1024,
        0, 0, 0, 0, 0, 0, 1.f, 0);

    // 4) feature maps -> fqH, fkH + per-block fk column partials (skp)
    feat_map2<<<dim3(16, 32, 2), blk, 0, stream>>>(
        QH, KH, WfqH, WfkH, bfq, bfk, fqH, fkH, skp);

    // 5) pred = (fq @ fk^T) / rowsum, normalization fully fused (skp path)
    mm_nt<128, 128, 64, 64><<<dim3(8, 8, 32), blk, 0, stream>>>(
        fqH, fkH, nullptr, skp, pred, nullptr, 128, 128, 128, 1024,
        (long)16 * S_ * 128, (long)S_ * 128,
        (long)16 * S_ * 128, (long)S_ * 128,
        16 * SS, SS, 1.f, 0);
}

// Round 8
// 438.464 us; speedup vs baseline: 1.0429x; 1.0237x over previous
//
#include <hip/hip_runtime.h>
#include <math.h>

constexpr int B_ = 2, S_ = 1024, DM_ = 1024, NH_ = 16, HD_ = 64;
constexpr long SD = (long)S_ * DM_;   // per-batch hidden stride (1M)
constexpr long SS = (long)S_ * S_;    // per-head attn stride (1M)

typedef _Float16 half8 __attribute__((ext_vector_type(8)));
typedef _Float16 half4 __attribute__((ext_vector_type(4)));
typedef float floatx4 __attribute__((ext_vector_type(4)));

// async global->LDS, 16 B per lane; LDS dst is wave-uniform base + lane*16
__device__ __forceinline__ void gl_lds16(const void* g, void* l) {
    __builtin_amdgcn_global_load_lds(
        (const __attribute__((address_space(1))) void*)g,
        (__attribute__((address_space(3))) void*)l, 16, 0, 0);
}

__device__ __forceinline__ void nt_store4(const floatx4& v, float* p) {
    __builtin_nontemporal_store(v, (floatx4*)p);
}

// ---------------------------------------------------------------------------
// Segmented fp32 -> fp16 convert for ALL inputs in one launch.
// ---------------------------------------------------------------------------
__global__ __launch_bounds__(256) void cvt_all(
    const float* __restrict__ hs,  const float* __restrict__ Wq,
    const float* __restrict__ Wk,  const float* __restrict__ Wv,
    const float* __restrict__ Wo,  const float* __restrict__ Wfq,
    const float* __restrict__ Wfk,
    _Float16* __restrict__ hsH, _Float16* __restrict__ WqH,
    _Float16* __restrict__ WkH, _Float16* __restrict__ WvH,
    _Float16* __restrict__ WoH, _Float16* __restrict__ WfqH,
    _Float16* __restrict__ WfkH)
{
    long i = (long)blockIdx.x * 256 + threadIdx.x;
    const float* src; _Float16* dst; long off;
    if (i < 524288)       { src = hs;  dst = hsH;  off = i; }
    else if (i < 786432)  { src = Wq;  dst = WqH;  off = i - 524288; }
    else if (i < 1048576) { src = Wk;  dst = WkH;  off = i - 786432; }
    else if (i < 1310720) { src = Wv;  dst = WvH;  off = i - 1048576; }
    else if (i < 1572864) { src = Wo;  dst = WoH;  off = i - 1310720; }
    else if (i < 1573888) { src = Wfq; dst = WfqH; off = i - 1572864; }
    else                  { src = Wfk; dst = WfkH; off = i - 1573888; }
    float4 v = ((const float4*)src)[off];
    half4 h = { (_Float16)v.x, (_Float16)v.y, (_Float16)v.z, (_Float16)v.w };
    ((half4*)dst)[off] = h;
}

// ---------------------------------------------------------------------------
// Unified NT MFMA GEMM (used for pred): C = scale*(A @ W^T) [*rsinv via skp].
// Swapped-operand epilogue -> float4/half4 stores.
// ---------------------------------------------------------------------------
template <int BM, int BN, int WM, int WN>
__global__ __launch_bounds__(256) void mm_nt(
    const _Float16* __restrict__ Ap, const _Float16* __restrict__ Wp,
    const float* __restrict__ bias, const float* __restrict__ skp,
    float* __restrict__ Cf,
    _Float16* __restrict__ Ch, int K, int lda, int ldw, int ldc,
    long sAb, long sAh, long sWb, long sWh, long sCb, long sCh,
    float scale, int mode)
{
    constexpr int MI = WM / 16, NI = WN / 16;
    const int z = blockIdx.z, b = z / NH_, h = z % NH_;
    const int wave = threadIdx.x >> 6, lane = threadIdx.x & 63;
    const int m0 = blockIdx.y * BM, n0 = blockIdx.x * BN;
    const int wm = (wave >> 1) * WM, wn = (wave & 1) * WN;
    const int r16 = lane & 15, quad = lane >> 4;

    const _Float16* Az = Ap + (long)b * sAb + (long)h * sAh;
    const _Float16* Wz = Wp + (long)b * sWb + (long)h * sWh;

    __shared__ __align__(16) _Float16 As[2 * BM * 32];
    __shared__ __align__(16) _Float16 Bs[2 * BN * 32];
    __shared__ float skz[128];
    __shared__ float rsinvs[BM];

    if (skp) {
        if (threadIdx.x < 128) {
            float s = 0.f;
#pragma unroll
            for (int m = 0; m < 16; ++m)
                s += skp[((long)z * 16 + m) * 128 + threadIdx.x];
            skz[threadIdx.x] = s;
        }
        __syncthreads();
        if (threadIdx.x < BM) {
            const _Float16* p = Az + (long)(m0 + threadIdx.x) * lda;
            float acc = 0.f;
#pragma unroll
            for (int d0 = 0; d0 < 128; d0 += 8) {
                half8 v = *(const half8*)(p + d0);
#pragma unroll
                for (int j = 0; j < 8; ++j)
                    acc = fmaf((float)v[j], skz[d0 + j], acc);
            }
            rsinvs[threadIdx.x] = 1.f / acc;
        }
    }

    floatx4 acc[MI][NI];
#pragma unroll
    for (int i = 0; i < MI; ++i)
#pragma unroll
        for (int j = 0; j < NI; ++j)
#pragma unroll
            for (int r = 0; r < 4; ++r) acc[i][j][r] = 0.f;

    for (int k0 = 0; k0 < K; k0 += 64) {
#pragma unroll
        for (int hf = 0; hf < 2; ++hf) {
#pragma unroll
            for (int c = wave * (BM / 64); c < (wave + 1) * (BM / 64); ++c) {
                const _Float16* g = Az + (long)(m0 + c * 16 + (lane >> 2)) * lda
                                    + k0 + hf * 32 + (lane & 3) * 8;
                gl_lds16(g, &As[hf * BM * 32 + c * 512]);
            }
#pragma unroll
            for (int c = wave * (BN / 64); c < (wave + 1) * (BN / 64); ++c) {
                const _Float16* g = Wz + (long)(n0 + c * 16 + (lane >> 2)) * ldw
                                    + k0 + hf * 32 + (lane & 3) * 8;
                gl_lds16(g, &Bs[hf * BN * 32 + c * 512]);
            }
        }
        __syncthreads();

#pragma unroll
        for (int hf = 0; hf < 2; ++hf) {
            half8 af[MI], bf8[NI];
#pragma unroll
            for (int i = 0; i < MI; ++i)
                af[i] = *(const half8*)&As[hf * BM * 32
                                           + (wm + i * 16 + r16) * 32 + quad * 8];
#pragma unroll
            for (int j = 0; j < NI; ++j)
                bf8[j] = *(const half8*)&Bs[hf * BN * 32
                                            + (wn + j * 16 + r16) * 32 + quad * 8];
#pragma unroll
            for (int i = 0; i < MI; ++i)
#pragma unroll
                for (int j = 0; j < NI; ++j)
                    acc[i][j] = __builtin_amdgcn_mfma_f32_16x16x32_f16(
                        bf8[j], af[i], acc[i][j], 0, 0, 0);   // SWAPPED
        }
        __syncthreads();
    }

    const long cb = (long)b * sCb + (long)h * sCh;
#pragma unroll
    for (int i = 0; i < MI; ++i) {
        const int row = m0 + wm + i * 16 + r16;
        const float rs = skp ? rsinvs[row - m0] : 1.f;
#pragma unroll
        for (int j = 0; j < NI; ++j) {
            const int col = n0 + wn + j * 16 + quad * 4;
            floatx4 v;
#pragma unroll
            for (int r = 0; r < 4; ++r) v[r] = acc[i][j][r] * scale;
            if (bias) {
                float4 bv = *(const float4*)&bias[col];
                v[0] += bv.x; v[1] += bv.y; v[2] += bv.z; v[3] += bv.w;
            }
            if (skp) {
#pragma unroll
                for (int r = 0; r < 4; ++r) v[r] *= rs;
            }
            if (mode == 0) {
                nt_store4(v, &Cf[cb + (long)row * ldc + col]);
            } else {
                half4 hv = { (_Float16)v[0], (_Float16)v[1],
                             (_Float16)v[2], (_Float16)v[3] };
                *(half4*)&Ch[cb + (long)row * ldc + col] = hv;
            }
        }
    }
}

// ---------------------------------------------------------------------------
// Fused QKV projection (unchanged from R5): swapped-operand epilogue.
// ---------------------------------------------------------------------------
__global__ __launch_bounds__(256) void qkv_proj(
    const _Float16* __restrict__ hsH,
    const _Float16* __restrict__ W0, const _Float16* __restrict__ W1,
    const _Float16* __restrict__ W2,
    const float* __restrict__ b0, const float* __restrict__ b1,
    const float* __restrict__ b2,
    _Float16* __restrict__ QH, _Float16* __restrict__ KH,
    _Float16* __restrict__ VtH)
{
    const int z = blockIdx.z;
    const _Float16* W = (z == 0) ? W0 : (z == 1) ? W1 : W2;
    const float* bias = (z == 0) ? b0 : (z == 1) ? b1 : b2;

    const int wave = threadIdx.x >> 6, lane = threadIdx.x & 63;
    const int m0 = blockIdx.y * 64, n0 = blockIdx.x * 128;
    const int wm = (wave >> 1) * 32, wn = (wave & 1) * 64;
    const int r16 = lane & 15, quad = lane >> 4;

    __shared__ __align__(16) _Float16 As[2 * 64 * 32];    // 8 KB
    __shared__ __align__(16) _Float16 Bs[2 * 128 * 32];   // 16 KB

    floatx4 acc[2][4];
#pragma unroll
    for (int i = 0; i < 2; ++i)
#pragma unroll
        for (int j = 0; j < 4; ++j)
#pragma unroll
            for (int r = 0; r < 4; ++r) acc[i][j][r] = 0.f;

    for (int k0 = 0; k0 < 1024; k0 += 64) {
#pragma unroll
        for (int hf = 0; hf < 2; ++hf) {
            const _Float16* ga = hsH + (long)(m0 + wave * 16 + (lane >> 2)) * 1024
                                 + k0 + hf * 32 + (lane & 3) * 8;
            gl_lds16(ga, &As[hf * 2048 + wave * 512]);
#pragma unroll
            for (int c = wave * 2; c < wave * 2 + 2; ++c) {
                const _Float16* gb = W + (long)(n0 + c * 16 + (lane >> 2)) * 1024
                                     + k0 + hf * 32 + (lane & 3) * 8;
                gl_lds16(gb, &Bs[hf * 4096 + c * 512]);
            }
        }
        __syncthreads();

#pragma unroll
        for (int hf = 0; hf < 2; ++hf) {
            half8 af[2], bf8[4];
#pragma unroll
            for (int i = 0; i < 2; ++i)
                af[i] = *(const half8*)&As[hf * 2048
                                           + (wm + i * 16 + r16) * 32 + quad * 8];
#pragma unroll
            for (int j = 0; j < 4; ++j)
                bf8[j] = *(const half8*)&Bs[hf * 4096
                                            + (wn + j * 16 + r16) * 32 + quad * 8];
#pragma unroll
            for (int i = 0; i < 2; ++i)
#pragma unroll
                for (int j = 0; j < 4; ++j)
                    acc[i][j] = __builtin_amdgcn_mfma_f32_16x16x32_f16(
                        bf8[j], af[i], acc[i][j], 0, 0, 0);   // SWAPPED
        }
        __syncthreads();
    }

    _Float16* dst = (z == 0) ? QH : KH;
#pragma unroll
    for (int i = 0; i < 2; ++i) {
        const int row = m0 + wm + i * 16 + r16;
#pragma unroll
        for (int j = 0; j < 4; ++j) {
            const int col = n0 + wn + j * 16 + quad * 4;
            float4 bv = *(const float4*)&bias[col];
            float v0 = acc[i][j][0] + bv.x, v1 = acc[i][j][1] + bv.y;
            float v2 = acc[i][j][2] + bv.z, v3 = acc[i][j][3] + bv.w;
            if (z < 2) {
                half4 hv = { (_Float16)v0, (_Float16)v1,
                             (_Float16)v2, (_Float16)v3 };
                *(half4*)&dst[(long)row * 1024 + col] = hv;
            } else {
                const int bb = row >> 10, s = row & 1023;
                const int hh = col >> 6, d0 = col & 63;
                float vv[4] = { v0, v1, v2, v3 };
#pragma unroll
                for (int r = 0; r < 4; ++r)
                    VtH[((((long)bb * 16 + hh) * 64 + d0 + r) << 10) | s] =
                        (_Float16)vv[r];
            }
        }
    }
}

// ---------------------------------------------------------------------------
// Fused attention, QBLK=16 / 256 thr / 32 KB LDS -> 4-5 blocks/CU (was 2).
// Swapped QK^T: acc[nj][r] = scores[m0+r16][c0+nj*16+quad*4+r].
// Wave w owns cols w*256..w*256+255. PV: wave -> d-slice w*16, full-K.
// ---------------------------------------------------------------------------
__global__ __launch_bounds__(256) void attn_fused(
    const _Float16* __restrict__ Q, const _Float16* __restrict__ K,
    const _Float16* __restrict__ Vt, float* __restrict__ trueA,
    _Float16* __restrict__ ctx)
{
    const int z = blockIdx.y, b = z >> 4, h = z & 15;
    const int m0 = blockIdx.x * 16;
    const int wave = threadIdx.x >> 6, lane = threadIdx.x & 63;
    const int r16 = lane & 15, quad = lane >> 4;
    const int c0 = wave * 256;

    __shared__ __align__(16) _Float16 Ps[16 * 1024];   // 32 KB, phase-aliased
    float* redmx = (float*)Ps;          // [4][16]
    float* redsm = (float*)Ps + 64;     // [4][16]

    const _Float16* Qb = Q + (long)b * SD + h * 64;
    const _Float16* Kb = K + (long)b * SD + h * 64;

    // Q fragment (B-operand after swap): row m0 + r16
    half8 qf[2];
#pragma unroll
    for (int ks = 0; ks < 2; ++ks)
        qf[ks] = *(const half8*)&Qb[(long)(m0 + r16) * DM_ + ks * 32 + quad * 8];

    floatx4 acc[16];
#pragma unroll
    for (int nj = 0; nj < 16; ++nj)
#pragma unroll
        for (int r = 0; r < 4; ++r) acc[nj][r] = 0.f;

#pragma unroll
    for (int ks = 0; ks < 2; ++ks) {
#pragma unroll
        for (int nj = 0; nj < 16; ++nj) {
            half8 kf = *(const half8*)&Kb[(long)(c0 + nj * 16 + r16) * DM_
                                          + ks * 32 + quad * 8];
            acc[nj] = __builtin_amdgcn_mfma_f32_16x16x32_f16(
                kf, qf[ks], acc[nj], 0, 0, 0);   // SWAPPED
        }
    }

    // ---- row max: 64 local values + shfl 16,32 + cross-wave (4) LDS reduce
    {
        float m = acc[0][0];
#pragma unroll
        for (int nj = 0; nj < 16; ++nj)
#pragma unroll
            for (int r = 0; r < 4; ++r) m = fmaxf(m, acc[nj][r]);
        m = fmaxf(m, __shfl_xor(m, 16, 64));
        m = fmaxf(m, __shfl_xor(m, 32, 64));
        if (quad == 0) redmx[wave * 16 + r16] = m;
    }
    __syncthreads();
    float mx = fmaxf(fmaxf(redmx[r16], redmx[16 + r16]),
                     fmaxf(redmx[32 + r16], redmx[48 + r16]));

    // ---- p = exp((s - max)/8), row sum
    {
        float s = 0.f;
#pragma unroll
        for (int nj = 0; nj < 16; ++nj)
#pragma unroll
            for (int r = 0; r < 4; ++r) {
                float p = __expf((acc[nj][r] - mx) * 0.125f);
                acc[nj][r] = p;
                s += p;
            }
        s += __shfl_xor(s, 16, 64);
        s += __shfl_xor(s, 32, 64);
        if (quad == 0) redsm[wave * 16 + r16] = s;
    }
    __syncthreads();
    const float inv = 1.f / (redsm[r16] + redsm[16 + r16]
                             + redsm[32 + r16] + redsm[48 + r16]);
    __syncthreads();   // red reads done; Ps region can be overwritten

    // ---- write normalized probs: trueA (float4 NT) + Ps (half4, XOR-swizzled)
    float* Ta = trueA + (long)z * SS + (long)m0 * S_;
    const int sw = (r16 & 7) << 3;
#pragma unroll
    for (int nj = 0; nj < 16; ++nj) {
        const int col = c0 + nj * 16 + quad * 4;
        floatx4 tv; half4 hv;
#pragma unroll
        for (int r = 0; r < 4; ++r) {
            float v = acc[nj][r] * inv;
            tv[r] = v;
            hv[r] = (_Float16)v;
        }
        nt_store4(tv, &Ta[(long)r16 * S_ + col]);
        *(half4*)&Ps[r16 * 1024 + (col ^ sw)] = hv;
    }
    __syncthreads();   // Ps complete

    // ---- ctx = P @ V (swapped): wave -> d-slice d0 = wave*16, full K
    const int d0 = wave * 16;
    const _Float16* Vb = Vt + ((long)z * 64 + d0 + r16) * (long)S_;
    floatx4 c2;
#pragma unroll
    for (int r = 0; r < 4; ++r) c2[r] = 0.f;

    const int swz = (r16 & 7) << 3;
#pragma unroll 8
    for (int k0 = 0; k0 < 1024; k0 += 32) {
        half8 pa = *(const half8*)&Ps[r16 * 1024 + ((k0 + quad * 8) ^ swz)];
        half8 vf = *(const half8*)&Vb[k0 + quad * 8];
        c2 = __builtin_amdgcn_mfma_f32_16x16x32_f16(vf, pa, c2, 0, 0, 0);
    }

    _Float16* Cb = ctx + (long)b * SD + h * 64;
    half4 cv = { (_Float16)c2[0], (_Float16)c2[1],
                 (_Float16)c2[2], (_Float16)c2[3] };
    *(half4*)&Cb[(long)(m0 + r16) * DM_ + d0 + quad * 4] = cv;
}

// ---------------------------------------------------------------------------
// tail_fused: out-proj (blocks 0..511) + feature maps (blocks 512..1535) in
// ONE launch — the two are independent; co-residency fills the machine and
// drops a launch gap. LDS is a union (41.3 KB = featmap's requirement).
// ---------------------------------------------------------------------------
__global__ __launch_bounds__(256) void tail_fused(
    const _Float16* __restrict__ ctxH, const _Float16* __restrict__ WoH,
    const float* __restrict__ bo, float* __restrict__ out0,
    const _Float16* __restrict__ QH, const _Float16* __restrict__ KH,
    const _Float16* __restrict__ Wfq, const _Float16* __restrict__ Wfk,
    const float* __restrict__ bfq, const float* __restrict__ bfk,
    _Float16* __restrict__ fqH, _Float16* __restrict__ fkH,
    float* __restrict__ skp)
{
    __shared__ __align__(16) char smem[41472];
    const int bid = blockIdx.x;

    if (bid < 512) {
        // ---- out-proj: C = ctx @ Wo^T + bo. BM=BN=64, WM=WN=32, K=1024.
        _Float16* As = (_Float16*)smem;             // 2*64*32 fp16 = 8 KB
        _Float16* Bs = (_Float16*)(smem + 8192);    // 8 KB
        const int bx = bid & 15, by = bid >> 4;
        const int wave = threadIdx.x >> 6, lane = threadIdx.x & 63;
        const int m0 = by * 64, n0 = bx * 64;
        const int wm = (wave >> 1) * 32, wn = (wave & 1) * 32;
        const int r16 = lane & 15, quad = lane >> 4;

        floatx4 acc[2][2];
#pragma unroll
        for (int i = 0; i < 2; ++i)
#pragma unroll
            for (int j = 0; j < 2; ++j)
#pragma unroll
                for (int r = 0; r < 4; ++r) acc[i][j][r] = 0.f;

        for (int k0 = 0; k0 < 1024; k0 += 64) {
#pragma unroll
            for (int hf = 0; hf < 2; ++hf) {
                const _Float16* ga = ctxH + (long)(m0 + wave * 16 + (lane >> 2)) * 1024
                                     + k0 + hf * 32 + (lane & 3) * 8;
                gl_lds16(ga, &As[hf * 2048 + wave * 512]);
                const _Float16* gb = WoH + (long)(n0 + wave * 16 + (lane >> 2)) * 1024
                                     + k0 + hf * 32 + (lane & 3) * 8;
                gl_lds16(gb, &Bs[hf * 2048 + wave * 512]);
            }
            __syncthreads();
#pragma unroll
            for (int hf = 0; hf < 2; ++hf) {
                half8 af[2], bf8[2];
#pragma unroll
                for (int i = 0; i < 2; ++i)
                    af[i] = *(const half8*)&As[hf * 2048
                                               + (wm + i * 16 + r16) * 32 + quad * 8];
#pragma unroll
                for (int j = 0; j < 2; ++j)
                    bf8[j] = *(const half8*)&Bs[hf * 2048
                                                + (wn + j * 16 + r16) * 32 + quad * 8];
#pragma unroll
                for (int i = 0; i < 2; ++i)
#pragma unroll
                    for (int j = 0; j < 2; ++j)
                        acc[i][j] = __builtin_amdgcn_mfma_f32_16x16x32_f16(
                            bf8[j], af[i], acc[i][j], 0, 0, 0);   // SWAPPED
            }
            __syncthreads();
        }

#pragma unroll
        for (int i = 0; i < 2; ++i) {
            const int row = m0 + wm + i * 16 + r16;
#pragma unroll
            for (int j = 0; j < 2; ++j) {
                const int col = n0 + wn + j * 16 + quad * 4;
                float4 bv = *(const float4*)&bo[col];
                floatx4 v;
                v[0] = acc[i][j][0] + bv.x; v[1] = acc[i][j][1] + bv.y;
                v[2] = acc[i][j][2] + bv.z; v[3] = acc[i][j][3] + bv.w;
                nt_store4(v, &out0[(long)row * 1024 + col]);
            }
        }
    } else {
        // ---- feature maps (identical math to feat_map2)
        const int fid = bid - 512;
        const int which = fid >> 9;          // 0 = fq, 1 = fk
        const int z = (fid >> 4) & 31, mb = fid & 15;
        const _Float16* Xh = which ? KH : QH;
        const _Float16* Wf = which ? Wfk : Wfq;
        const float* bf    = which ? bfk : bfq;
        _Float16* outH     = which ? fkH : fqH;

        float (*Xs)[65] = (float(*)[65])smem;              // 16640 B
        float (*Ws)[65] = (float(*)[65])(smem + 16640);    // 16640 B
        float (*red)[128] = (float(*)[128])(smem + 33280); // 8192 B

        const int b = z >> 4, h = z & 15;
        const int m0 = mb * 64;
        const _Float16* Xb = Xh + (long)b * SD + h * 64;
        for (int i = threadIdx.x; i < 4096; i += 256) {
            int r = i >> 6, c = i & 63;
            Xs[r][c] = (float)Xb[(long)(m0 + r) * 1024 + c];
            Ws[r][c] = (float)Wf[i];
        }
        __syncthreads();
        const int tmg = threadIdx.x >> 4;
        const int tm = tmg * 4, tn = (threadIdx.x & 15) * 4;
        float acc[4][4] = {{0.f}};
        for (int k = 0; k < 64; ++k) {
            float xv[4], wv[4];
#pragma unroll
            for (int i = 0; i < 4; ++i) xv[i] = Xs[tm + i][k];
#pragma unroll
            for (int j = 0; j < 4; ++j) wv[j] = Ws[tn + j][k];
#pragma unroll
            for (int i = 0; i < 4; ++i)
#pragma unroll
                for (int j = 0; j < 4; ++j)
                    acc[i][j] = fmaf(xv[i], wv[j], acc[i][j]);
        }
        float sp[4] = {0.f, 0.f, 0.f, 0.f}, sn[4] = {0.f, 0.f, 0.f, 0.f};
#pragma unroll
        for (int i = 0; i < 4; ++i) {
            long base = ((long)z * S_ + m0 + tm + i) * 128;
#pragma unroll
            for (int j = 0; j < 4; ++j) {
                float y = acc[i][j] + bf[tn + j];
                float ep = expf(y), en = expf(-y);
                outH[base + tn + j]      = (_Float16)ep;
                outH[base + 64 + tn + j] = (_Float16)en;
                sp[j] += ep; sn[j] += en;
            }
        }
        if (which) {
#pragma unroll
            for (int j = 0; j < 4; ++j) {
                red[tmg][tn + j]      = sp[j];
                red[tmg][64 + tn + j] = sn[j];
            }
            __syncthreads();
            if (threadIdx.x < 128) {
                float s = 0.f;
#pragma unroll
                for (int g = 0; g < 16; ++g) s += red[g][threadIdx.x];
                skp[((long)z * 16 + mb) * 128 + threadIdx.x] = s;
            }
        }
    }
}

// ---------------------------------------------------------------------------
extern "C" void kernel_launch(void* const* d_in, const int* in_sizes, int n_in,
                              void* d_out, int out_size, void* d_ws, size_t ws_size,
                              hipStream_t stream)
{
    (void)in_sizes; (void)n_in; (void)out_size; (void)ws_size;

    const float* hs  = (const float*)d_in[0];
    const float* Wq  = (const float*)d_in[1];
    const float* bq  = (const float*)d_in[2];
    const float* Wk  = (const float*)d_in[3];
    const float* bk  = (const float*)d_in[4];
    const float* Wv  = (const float*)d_in[5];
    const float* bv  = (const float*)d_in[6];
    const float* Wo  = (const float*)d_in[7];
    const float* bo  = (const float*)d_in[8];
    const float* Wfq = (const float*)d_in[9];
    const float* bfq = (const float*)d_in[10];
    const float* Wfk = (const float*)d_in[11];
    const float* bfk = (const float*)d_in[12];

    float* out0  = (float*)d_out;                       // (B,S,DM)
    float* pred  = out0 + (long)B_ * S_ * DM_;          // (B,H,S,S)
    float* trueA = pred + (long)B_ * NH_ * S_ * S_;     // (B,H,S,S)

    // workspace carve (halves), ~45 MB total
    _Float16* hsH  = (_Float16*)d_ws;                   // 2M
    _Float16* WqH  = hsH + 2 * 1024 * 1024;             // 1M each
    _Float16* WkH  = WqH + 1024 * 1024;
    _Float16* WvH  = WkH + 1024 * 1024;
    _Float16* WoH  = WvH + 1024 * 1024;
    _Float16* WfqH = WoH + 1024 * 1024;                 // 4096 each
    _Float16* WfkH = WfqH + 4096;
    _Float16* QH   = WfkH + 4096;                       // 2M each
    _Float16* KH   = QH + 2 * 1024 * 1024;
    _Float16* VtH  = KH + 2 * 1024 * 1024;              // (B,H,D,S)
    _Float16* ctxH = VtH + 2 * 1024 * 1024;             // (B,S,DM)
    _Float16* fqH  = ctxH + 2 * 1024 * 1024;            // (B,H,S,128)
    _Float16* fkH  = fqH + (long)B_ * NH_ * S_ * 128;

    // skp (256 KB) reuses WqH region (dead after qkv_proj, written by
    // tail_fused). Fully overwritten with plain stores before being read.
    float* skp = (float*)WqH;

    const dim3 blk(256);

    // 0) all fp32 -> fp16 input conversions, one launch
    cvt_all<<<6152, blk, 0, stream>>>(
        hs, Wq, Wk, Wv, Wo, Wfq, Wfk,
        hsH, WqH, WkH, WvH, WoH, WfqH, WfkH);

    // 1) fused QKV projection (V transposed per head)
    qkv_proj<<<dim3(8, 32, 3), blk, 0, stream>>>(
        hsH, WqH, WkH, WvH, bq, bk, bv, QH, KH, VtH);

    // 2) fused scores -> softmax -> trueA + ctx (QBLK=16, 4-5 blocks/CU)
    attn_fused<<<dim3(64, 32), blk, 0, stream>>>(
        QH, KH, VtH, trueA, ctxH);

    // 3) out-proj + feature maps + skp partials, one co-resident launch
    tail_fused<<<1536, blk, 0, stream>>>(
        ctxH, WoH, bo, out0,
        QH, KH, WfqH, WfkH, bfq, bfk, fqH, fkH, skp);

    // 4) pred = (fq @ fk^T) / rowsum, normalization fully fused (skp path)
    mm_nt<128, 128, 64, 64><<<dim3(8, 8, 32), blk, 0, stream>>>(
        fqH, fkH, nullptr, skp, pred, nullptr, 128, 128, 128, 1024,
        (long)16 * S_ * 128, (long)S_ * 128,
        (long)16 * S_ * 128, (long)S_ * 128,
        16 * SS, SS, 1.f, 0);
}